// Round 14
// baseline (89.700 us; speedup 1.0000x reference)
//
#include <hip/hip_runtime.h>
#include <hip/hip_fp16.h>
#include <math.h>

#define BB 2
#define CC 256
#define TT 16
#define HH 64
#define WW 64
#define NN 128
#define OT 2
#define OH 7
#define OW 7
#define PP (TT * HH * WW)          // 65536 positions per (b,c)
#define BIN (OT * OH * OW)         // 98 bins per (n,c)
#define CU2 (CC / 2)               // 128 uints per position (512B row)
#define NQ (NN * OH * OW)          // 6272 q-groups (n, oh, ow)
#define GRIDP (NQ / 2)             // 3136 pool blocks: 2 q-groups x 2 t-chunks

#define FEATT_BYTES ((size_t)BB * CC * PP * 2)            // 64 MiB
#define STAGE_OFF   FEATT_BYTES
#define STAGE_BYTES ((size_t)NN * BIN * CC * 4)           // 12.8 MB
#define WS_NEED     (STAGE_OFF + STAGE_BYTES)

typedef _Float16 hf2 __attribute__((ext_vector_type(2)));

// ------- transpose + downconvert: (B,C,T,H,W) f32 -> (B,T,H,W,C) fp16 -------
__global__ __launch_bounds__(256) void transpose_f16_kernel(
    const float* __restrict__ in, unsigned int* __restrict__ outt /*f16x2*/)
{
    __shared__ float tile[64][65];
    int pb = blockIdx.x & 1023;          // p-tile (1024)
    int cb = (blockIdx.x >> 10) & 3;     // c-tile (4)
    int b  = blockIdx.x >> 12;           // batch (2)

    int tx = threadIdx.x & 63;           // p within tile
    int wv = threadIdx.x >> 6;           // 0..3
    const float* src = in + ((size_t)b * CC + cb * 64) * PP + pb * 64;
    #pragma unroll
    for (int r = 0; r < 16; ++r) {
        int c = wv + r * 4;
        tile[tx][c] = src[(size_t)c * PP + tx];
    }
    __syncthreads();

    int cp   = threadIdx.x & 31;         // c-pair 0..31 (covers 64 c)
    int prow = threadIdx.x >> 5;         // 0..7
    size_t base = ((size_t)b * PP + (size_t)pb * 64) * CC + cb * 64;
    #pragma unroll
    for (int r = 0; r < 8; ++r) {
        int p = prow + r * 8;
        __half h0 = __float2half(tile[p][2 * cp]);
        __half h1 = __float2half(tile[p][2 * cp + 1]);
        unsigned int u = (unsigned int)__half_as_ushort(h0)
                       | ((unsigned int)__half_as_ushort(h1) << 16);
        outt[(base + (size_t)p * CC) / 2 + cp] = u;
    }
}

// ---- pipelined gather loop: NX = exact x-width, D = pipeline depth ----
// niter <= D: issue ALL groups back-to-back (full MLP for short waves), then
// consume. niter > D: rotating D-deep pipeline. Static buffer indices only.
template<int NX, int D>
__device__ __forceinline__ void pool_loop(
    const unsigned int* __restrict__ p, int niter, int ny,
    int ystep, int tstep, hf2& m0, hf2& m1, hf2& m2, hf2& m3)
{
    uint4 v[D][NX];
    int iy = 0;

#define PLOAD(d)                                            \
    _Pragma("unroll")                                       \
    for (int j = 0; j < NX; ++j)                            \
        v[d][j] = *(const uint4*)(p + j * CU2);

#define PADV()                                              \
    do { if (++iy == ny) { iy = 0; p += tstep; } else p += ystep; } while (0)

#define PCONS(d)                                            \
    _Pragma("unroll")                                       \
    for (int j = 0; j < NX; ++j) {                          \
        m0 = __builtin_elementwise_max(m0, __builtin_bit_cast(hf2, v[d][j].x)); \
        m1 = __builtin_elementwise_max(m1, __builtin_bit_cast(hf2, v[d][j].y)); \
        m2 = __builtin_elementwise_max(m2, __builtin_bit_cast(hf2, v[d][j].z)); \
        m3 = __builtin_elementwise_max(m3, __builtin_bit_cast(hf2, v[d][j].w)); \
    }

    if (niter <= D) {
        #pragma unroll
        for (int d = 0; d < D; ++d)
            if (d < niter) { PLOAD(d); PADV(); }
        #pragma unroll
        for (int d = 0; d < D; ++d)
            if (d < niter) { PCONS(d); }
    } else {
        #pragma unroll
        for (int d = 0; d < D; ++d) { PLOAD(d); PADV(); }
        int M = (niter - D) / D;
        int r = (niter - D) % D;
        for (int s = 0; s < M; ++s) {
            #pragma unroll
            for (int d = 0; d < D; ++d) { PCONS(d); PLOAD(d); PADV(); }
        }
        #pragma unroll
        for (int d = 0; d < D; ++d)
            if (d < r) { PCONS(d); PLOAD(d); PADV(); }
        #pragma unroll
        for (int d = 0; d < D; ++d) PCONS(d);   // max commutative
    }
#undef PLOAD
#undef PADV
#undef PCONS
}

// ------- pooling: block = 4 waves = 2 q-groups x 2 t-chunks ----------------
// Output goes to a (n,bin,c) staging buffer with fully-coalesced stores.
__global__ __launch_bounds__(256) void roipool3d_f16_kernel(
    const unsigned int* __restrict__ featt,  // (B,T,H,W,C) f16 as uint pairs
    const float* __restrict__ rois,
    float* __restrict__ stage)               // (N, BIN, C) f32
{
    __shared__ unsigned int comb[2][64][4];

    int wg  = blockIdx.x;
    int swz = (wg & 7) * (GRIDP / 8) + (wg >> 3);   // bijective: 3136 % 8 == 0
    int wave  = threadIdx.x >> 6;      // 0..3
    int qslot = wave >> 1;
    int tc    = wave & 1;
    int lane = threadIdx.x & 63;
    int half = lane >> 5;              // = ot
    int cl   = lane & 31;              // c-group: 8 channels
    int q    = swz * 2 + qslot;        // (roi, oh, ow)
    int rem  = q % (OH * OW);
    int n    = q / (OH * OW);
    int oh   = rem / OW;
    int ow   = rem % OW;

    const float* r = rois + n * 7;
    int b  = (int)r[0];
    int t1 = (int)r[1];
    int x1 = (int)r[2];
    int y1 = (int)r[3];
    int t2 = (int)r[4];
    int x2 = (int)r[5];
    int y2 = (int)r[6];
    int lt = t2 - t1 + 1, lh = y2 - y1 + 1, lw = x2 - x1 + 1;

    int nt_full = (lt + 1) >> 1;       // per-ot t-length (same both halves)
    int ntc0 = (nt_full + 1) >> 1;     // tc=0 chunk length
    int nt_c = tc ? (nt_full - ntc0) : ntc0;      // >= 1
    int t0 = t1 + (half ? (lt >> 1) : 0) + (tc ? ntc0 : 0);

    int hs = (oh * lh) / OH, he = ((oh + 1) * lh + OH - 1) / OH;
    int ws = (ow * lw) / OW, we = ((ow + 1) * lw + OW - 1) / OW;
    int ny = he - hs;                  // 2..6
    int nx = we - ws;                  // 2..6 (wave-uniform)
    int niter = nt_c * ny;             // >= 2

    const unsigned int* p = featt
        + (size_t)((size_t)b * PP + (size_t)((t0 * HH + (y1 + hs)) * WW + (x1 + ws))) * CU2
        + cl * 4;

    const int ystep = WW * CU2;
    const int tstep = (HH - (ny - 1)) * WW * CU2;

    hf2 m0; m0[0] = (_Float16)(-65504.0f); m0[1] = m0[0];
    hf2 m1 = m0, m2 = m0, m3 = m0;

    switch (nx) {
        case 2:  pool_loop<2, 8>(p, niter, ny, ystep, tstep, m0, m1, m2, m3); break;
        case 3:  pool_loop<3, 6>(p, niter, ny, ystep, tstep, m0, m1, m2, m3); break;
        case 4:  pool_loop<4, 5>(p, niter, ny, ystep, tstep, m0, m1, m2, m3); break;
        case 5:  pool_loop<5, 4>(p, niter, ny, ystep, tstep, m0, m1, m2, m3); break;
        default: pool_loop<6, 3>(p, niter, ny, ystep, tstep, m0, m1, m2, m3); break;
    }

    // ---- combine tc partners via LDS; tc=0 writes ----
    if (tc) {
        comb[qslot][lane][0] = __builtin_bit_cast(unsigned int, m0);
        comb[qslot][lane][1] = __builtin_bit_cast(unsigned int, m1);
        comb[qslot][lane][2] = __builtin_bit_cast(unsigned int, m2);
        comb[qslot][lane][3] = __builtin_bit_cast(unsigned int, m3);
    }
    __syncthreads();
    if (!tc) {
        m0 = __builtin_elementwise_max(m0, __builtin_bit_cast(hf2, comb[qslot][lane][0]));
        m1 = __builtin_elementwise_max(m1, __builtin_bit_cast(hf2, comb[qslot][lane][1]));
        m2 = __builtin_elementwise_max(m2, __builtin_bit_cast(hf2, comb[qslot][lane][2]));
        m3 = __builtin_elementwise_max(m3, __builtin_bit_cast(hf2, comb[qslot][lane][3]));

        int c0 = cl * 8;
        int bin = half * (OH * OW) + rem;
        float4 s0 = { (float)m0[0], (float)m0[1], (float)m1[0], (float)m1[1] };
        float4 s1 = { (float)m2[0], (float)m2[1], (float)m3[0], (float)m3[1] };
        float* sp = stage + ((size_t)n * BIN + bin) * CC + c0;
        *(float4*)sp       = s0;
        *(float4*)(sp + 4) = s1;
    }
}

// ------- untranspose: (N, BIN, C) -> (N, C, BIN), both sides coalesced -------
__global__ __launch_bounds__(128) void untranspose_kernel(
    const float* __restrict__ stage, float* __restrict__ out)
{
    __shared__ float t[32][99];
    int n  = blockIdx.x >> 3;
    int c0 = (blockIdx.x & 7) * 32;
    const float* sp = stage + (size_t)n * BIN * CC + c0;
    for (int k = threadIdx.x; k < BIN * 32; k += 128) {
        int bin = k >> 5, c = k & 31;
        t[c][bin] = sp[(size_t)bin * CC + c];
    }
    __syncthreads();
    float* op = out + ((size_t)n * CC + c0) * BIN;
    for (int c = 0; c < 32; ++c) {
        if (threadIdx.x < BIN)
            op[(size_t)c * BIN + threadIdx.x] = t[c][threadIdx.x];
    }
}

// ---------------- fallback if ws too small: direct fp32 gather ----------------
#define NXCD 8
#define C_PER_XCD (CC / NXCD)
#define PLANE (NN * BIN)
#define BLOCKS_PER_C (PLANE / 256)
__global__ __launch_bounds__(256) void roipool3d_fb_kernel(
    const float* __restrict__ feat, const float* __restrict__ rois,
    float* __restrict__ out)
{
    int wg = blockIdx.x, xcd = wg % NXCD, i = wg / NXCD;
    int c = xcd * C_PER_XCD + i / BLOCKS_PER_C;
    int p = (i % BLOCKS_PER_C) * 256 + threadIdx.x;
    int n = p / BIN, rem = p % BIN;
    int ot = rem / (OH * OW), oh = (rem / OW) % OH, ow = rem % OW;
    const float* r = rois + n * 7;
    int b = (int)r[0], t1 = (int)r[1], x1 = (int)r[2], y1 = (int)r[3];
    int t2 = (int)r[4], x2 = (int)r[5], y2 = (int)r[6];
    int lt = t2 - t1 + 1, lh = y2 - y1 + 1, lw = x2 - x1 + 1;
    int ts = (ot * lt) / OT, te = ((ot + 1) * lt + OT - 1) / OT;
    int hs = (oh * lh) / OH, he = ((oh + 1) * lh + OH - 1) / OH;
    int ws = (ow * lw) / OW, we = ((ow + 1) * lw + OW - 1) / OW;
    const float* fbase = feat + ((size_t)b * CC + c) * PP;
    float m = -INFINITY;
    for (int t = t1 + ts; t < t1 + te; ++t)
        for (int y = y1 + hs; y < y1 + he; ++y)
            for (int x = x1 + ws; x < x1 + we; ++x)
                m = fmaxf(m, fbase[t * (HH * WW) + y * WW + x]);
    out[((size_t)n * CC + c) * BIN + rem] = m;
}

extern "C" void kernel_launch(void* const* d_in, const int* in_sizes, int n_in,
                              void* d_out, int out_size, void* d_ws, size_t ws_size,
                              hipStream_t stream) {
    const float* feat = (const float*)d_in[0];
    const float* rois = (const float*)d_in[1];
    float* out = (float*)d_out;

    if (ws_size >= WS_NEED && d_ws) {
        unsigned int* featt = (unsigned int*)d_ws;
        float* stage = (float*)((char*)d_ws + STAGE_OFF);
        transpose_f16_kernel<<<BB * 4 * 1024, 256, 0, stream>>>(feat, featt);
        roipool3d_f16_kernel<<<GRIDP, 256, 0, stream>>>(featt, rois, stage);
        untranspose_kernel<<<NN * 8, 128, 0, stream>>>(stage, out);
    } else {
        roipool3d_fb_kernel<<<NXCD * C_PER_XCD * BLOCKS_PER_C, 256, 0, stream>>>(
            feat, rois, out);
    }
}

// Round 15
// 89.366 us; speedup vs baseline: 1.0037x; 1.0037x over previous
//
#include <hip/hip_runtime.h>
#include <hip/hip_fp16.h>
#include <math.h>

#define BB 2
#define CC 256
#define TT 16
#define HH 64
#define WW 64
#define NN 128
#define OT 2
#define OH 7
#define OW 7
#define PP (TT * HH * WW)          // 65536 positions per (b,c)
#define BIN (OT * OH * OW)         // 98 bins per (n,c)
#define CU2 (CC / 2)               // 128 uints per position (512B row)
#define NQ (NN * OH * OW)          // 6272 q-groups (n, oh, ow)
#define GRIDP (NQ / 2)             // 3136 pool blocks: 2 q-groups x 2 t-chunks

#define FEATT_BYTES ((size_t)BB * CC * PP * 2)            // 64 MiB
#define STAGE_OFF   FEATT_BYTES
#define STAGE_BYTES ((size_t)NN * BIN * CC * 4)           // 12.8 MB
#define WS_NEED     (STAGE_OFF + STAGE_BYTES)

typedef _Float16 hf2 __attribute__((ext_vector_type(2)));

// ------- transpose + downconvert: (B,C,T,H,W) f32 -> (B,T,H,W,C) fp16 -------
__global__ __launch_bounds__(256) void transpose_f16_kernel(
    const float* __restrict__ in, unsigned int* __restrict__ outt /*f16x2*/)
{
    __shared__ float tile[64][65];
    int pb = blockIdx.x & 1023;          // p-tile (1024)
    int cb = (blockIdx.x >> 10) & 3;     // c-tile (4)
    int b  = blockIdx.x >> 12;           // batch (2)

    int tx = threadIdx.x & 63;           // p within tile
    int wv = threadIdx.x >> 6;           // 0..3
    const float* src = in + ((size_t)b * CC + cb * 64) * PP + pb * 64;
    #pragma unroll
    for (int r = 0; r < 16; ++r) {
        int c = wv + r * 4;
        tile[tx][c] = src[(size_t)c * PP + tx];
    }
    __syncthreads();

    int cp   = threadIdx.x & 31;         // c-pair 0..31 (covers 64 c)
    int prow = threadIdx.x >> 5;         // 0..7
    size_t base = ((size_t)b * PP + (size_t)pb * 64) * CC + cb * 64;
    #pragma unroll
    for (int r = 0; r < 8; ++r) {
        int p = prow + r * 8;
        __half h0 = __float2half(tile[p][2 * cp]);
        __half h1 = __float2half(tile[p][2 * cp + 1]);
        unsigned int u = (unsigned int)__half_as_ushort(h0)
                       | ((unsigned int)__half_as_ushort(h1) << 16);
        outt[(base + (size_t)p * CC) / 2 + cp] = u;
    }
}

// ---- pipelined gather loop: NX = exact x-width, D = pipeline depth ----
// niter <= D: issue ALL groups back-to-back, then consume (short waves get
// full MLP). niter > D: rotating D-deep pipeline. Static indices only.
template<int NX, int D>
__device__ __forceinline__ void pool_loop(
    const unsigned int* __restrict__ p, int niter, int ny,
    int ystep, int tstep, hf2& m0, hf2& m1, hf2& m2, hf2& m3)
{
    uint4 v[D][NX];
    int iy = 0;

#define PLOAD(d)                                            \
    _Pragma("unroll")                                       \
    for (int j = 0; j < NX; ++j)                            \
        v[d][j] = *(const uint4*)(p + j * CU2);

#define PADV()                                              \
    do { if (++iy == ny) { iy = 0; p += tstep; } else p += ystep; } while (0)

#define PCONS(d)                                            \
    _Pragma("unroll")                                       \
    for (int j = 0; j < NX; ++j) {                          \
        m0 = __builtin_elementwise_max(m0, __builtin_bit_cast(hf2, v[d][j].x)); \
        m1 = __builtin_elementwise_max(m1, __builtin_bit_cast(hf2, v[d][j].y)); \
        m2 = __builtin_elementwise_max(m2, __builtin_bit_cast(hf2, v[d][j].z)); \
        m3 = __builtin_elementwise_max(m3, __builtin_bit_cast(hf2, v[d][j].w)); \
    }

    if (niter <= D) {
        #pragma unroll
        for (int d = 0; d < D; ++d)
            if (d < niter) { PLOAD(d); PADV(); }
        #pragma unroll
        for (int d = 0; d < D; ++d)
            if (d < niter) { PCONS(d); }
    } else {
        #pragma unroll
        for (int d = 0; d < D; ++d) { PLOAD(d); PADV(); }
        int M = (niter - D) / D;
        int r = (niter - D) % D;
        for (int s = 0; s < M; ++s) {
            #pragma unroll
            for (int d = 0; d < D; ++d) { PCONS(d); PLOAD(d); PADV(); }
        }
        #pragma unroll
        for (int d = 0; d < D; ++d)
            if (d < r) { PCONS(d); PLOAD(d); PADV(); }
        #pragma unroll
        for (int d = 0; d < D; ++d) PCONS(d);   // max commutative
    }
#undef PLOAD
#undef PADV
#undef PCONS
}

// ------- pooling: block = 4 waves = 2 q-groups x 2 t-chunks ----------------
__global__ __launch_bounds__(256) void roipool3d_f16_kernel(
    const unsigned int* __restrict__ featt,  // (B,T,H,W,C) f16 as uint pairs
    const float* __restrict__ rois,
    float* __restrict__ stage)               // (N, BIN, C) f32
{
    __shared__ unsigned int comb[2][64][4];

    int wg  = blockIdx.x;
    int swz = (wg & 7) * (GRIDP / 8) + (wg >> 3);   // bijective: 3136 % 8 == 0
    int wave  = threadIdx.x >> 6;      // 0..3
    int qslot = wave >> 1;
    int tc    = wave & 1;
    int lane = threadIdx.x & 63;
    int half = lane >> 5;              // = ot
    int cl   = lane & 31;              // c-group: 8 channels
    int q    = swz * 2 + qslot;        // (roi, oh, ow)
    int rem  = q % (OH * OW);
    int n    = q / (OH * OW);
    int oh   = rem / OW;
    int ow   = rem % OW;

    const float* r = rois + n * 7;
    int b  = (int)r[0];
    int t1 = (int)r[1];
    int x1 = (int)r[2];
    int y1 = (int)r[3];
    int t2 = (int)r[4];
    int x2 = (int)r[5];
    int y2 = (int)r[6];
    int lt = t2 - t1 + 1, lh = y2 - y1 + 1, lw = x2 - x1 + 1;

    int nt_full = (lt + 1) >> 1;       // per-ot t-length (same both halves)
    int ntc0 = (nt_full + 1) >> 1;     // tc=0 chunk length
    int nt_c = tc ? (nt_full - ntc0) : ntc0;      // >= 1
    int t0 = t1 + (half ? (lt >> 1) : 0) + (tc ? ntc0 : 0);

    int hs = (oh * lh) / OH, he = ((oh + 1) * lh + OH - 1) / OH;
    int ws = (ow * lw) / OW, we = ((ow + 1) * lw + OW - 1) / OW;
    int ny = he - hs;                  // 2..6
    int nx = we - ws;                  // 2..6 (wave-uniform)
    int niter = nt_c * ny;             // >= 2

    const unsigned int* p = featt
        + (size_t)((size_t)b * PP + (size_t)((t0 * HH + (y1 + hs)) * WW + (x1 + ws))) * CU2
        + cl * 4;

    const int ystep = WW * CU2;
    const int tstep = (HH - (ny - 1)) * WW * CU2;

    hf2 m0; m0[0] = (_Float16)(-65504.0f); m0[1] = m0[0];
    hf2 m1 = m0, m2 = m0, m3 = m0;

    switch (nx) {
        case 2:  pool_loop<2, 6>(p, niter, ny, ystep, tstep, m0, m1, m2, m3); break;
        case 3:  pool_loop<3, 4>(p, niter, ny, ystep, tstep, m0, m1, m2, m3); break;
        case 4:  pool_loop<4, 3>(p, niter, ny, ystep, tstep, m0, m1, m2, m3); break;
        case 5:  pool_loop<5, 2>(p, niter, ny, ystep, tstep, m0, m1, m2, m3); break;
        default: pool_loop<6, 2>(p, niter, ny, ystep, tstep, m0, m1, m2, m3); break;
    }

    // ---- combine tc partners via LDS; tc=0 writes ----
    if (tc) {
        comb[qslot][lane][0] = __builtin_bit_cast(unsigned int, m0);
        comb[qslot][lane][1] = __builtin_bit_cast(unsigned int, m1);
        comb[qslot][lane][2] = __builtin_bit_cast(unsigned int, m2);
        comb[qslot][lane][3] = __builtin_bit_cast(unsigned int, m3);
    }
    __syncthreads();
    if (!tc) {
        m0 = __builtin_elementwise_max(m0, __builtin_bit_cast(hf2, comb[qslot][lane][0]));
        m1 = __builtin_elementwise_max(m1, __builtin_bit_cast(hf2, comb[qslot][lane][1]));
        m2 = __builtin_elementwise_max(m2, __builtin_bit_cast(hf2, comb[qslot][lane][2]));
        m3 = __builtin_elementwise_max(m3, __builtin_bit_cast(hf2, comb[qslot][lane][3]));

        int c0 = cl * 8;
        int bin = half * (OH * OW) + rem;
        float4 s0 = { (float)m0[0], (float)m0[1], (float)m1[0], (float)m1[1] };
        float4 s1 = { (float)m2[0], (float)m2[1], (float)m3[0], (float)m3[1] };
        float* sp = stage + ((size_t)n * BIN + bin) * CC + c0;
        *(float4*)sp       = s0;
        *(float4*)(sp + 4) = s1;
    }
}

// ------- untranspose: (N, BIN, C) -> (N, C, BIN), both sides coalesced -------
__global__ __launch_bounds__(128) void untranspose_kernel(
    const float* __restrict__ stage, float* __restrict__ out)
{
    __shared__ float t[32][99];
    int n  = blockIdx.x >> 3;
    int c0 = (blockIdx.x & 7) * 32;
    const float* sp = stage + (size_t)n * BIN * CC + c0;
    for (int k = threadIdx.x; k < BIN * 32; k += 128) {
        int bin = k >> 5, c = k & 31;
        t[c][bin] = sp[(size_t)bin * CC + c];
    }
    __syncthreads();
    float* op = out + ((size_t)n * CC + c0) * BIN;
    for (int c = 0; c < 32; ++c) {
        if (threadIdx.x < BIN)
            op[(size_t)c * BIN + threadIdx.x] = t[c][threadIdx.x];
    }
}

// ---------------- fallback if ws too small: direct fp32 gather ----------------
#define NXCD 8
#define C_PER_XCD (CC / NXCD)
#define PLANE (NN * BIN)
#define BLOCKS_PER_C (PLANE / 256)
__global__ __launch_bounds__(256) void roipool3d_fb_kernel(
    const float* __restrict__ feat, const float* __restrict__ rois,
    float* __restrict__ out)
{
    int wg = blockIdx.x, xcd = wg % NXCD, i = wg / NXCD;
    int c = xcd * C_PER_XCD + i / BLOCKS_PER_C;
    int p = (i % BLOCKS_PER_C) * 256 + threadIdx.x;
    int n = p / BIN, rem = p % BIN;
    int ot = rem / (OH * OW), oh = (rem / OW) % OH, ow = rem % OW;
    const float* r = rois + n * 7;
    int b = (int)r[0], t1 = (int)r[1], x1 = (int)r[2], y1 = (int)r[3];
    int t2 = (int)r[4], x2 = (int)r[5], y2 = (int)r[6];
    int lt = t2 - t1 + 1, lh = y2 - y1 + 1, lw = x2 - x1 + 1;
    int ts = (ot * lt) / OT, te = ((ot + 1) * lt + OT - 1) / OT;
    int hs = (oh * lh) / OH, he = ((oh + 1) * lh + OH - 1) / OH;
    int ws = (ow * lw) / OW, we = ((ow + 1) * lw + OW - 1) / OW;
    const float* fbase = feat + ((size_t)b * CC + c) * PP;
    float m = -INFINITY;
    for (int t = t1 + ts; t < t1 + te; ++t)
        for (int y = y1 + hs; y < y1 + he; ++y)
            for (int x = x1 + ws; x < x1 + we; ++x)
                m = fmaxf(m, fbase[t * (HH * WW) + y * WW + x]);
    out[((size_t)n * CC + c) * BIN + rem] = m;
}

extern "C" void kernel_launch(void* const* d_in, const int* in_sizes, int n_in,
                              void* d_out, int out_size, void* d_ws, size_t ws_size,
                              hipStream_t stream) {
    const float* feat = (const float*)d_in[0];
    const float* rois = (const float*)d_in[1];
    float* out = (float*)d_out;

    if (ws_size >= WS_NEED && d_ws) {
        unsigned int* featt = (unsigned int*)d_ws;
        float* stage = (float*)((char*)d_ws + STAGE_OFF);
        transpose_f16_kernel<<<BB * 4 * 1024, 256, 0, stream>>>(feat, featt);
        roipool3d_f16_kernel<<<GRIDP, 256, 0, stream>>>(featt, rois, stage);
        untranspose_kernel<<<NN * 8, 128, 0, stream>>>(stage, out);
    } else {
        roipool3d_fb_kernel<<<NXCD * C_PER_XCD * BLOCKS_PER_C, 256, 0, stream>>>(
            feat, rois, out);
    }
}

// Round 16
// 83.828 us; speedup vs baseline: 1.0700x; 1.0661x over previous
//
#include <hip/hip_runtime.h>
#include <hip/hip_fp16.h>
#include <math.h>

#define BB 2
#define CC 256
#define TT 16
#define HH 64
#define WW 64
#define NN 128
#define OT 2
#define OH 7
#define OW 7
#define PP (TT * HH * WW)          // 65536 positions per (b,c)
#define BIN (OT * OH * OW)         // 98 bins per (n,c)
#define CU2 (CC / 2)               // 128 uints per position (512B row)
#define NQ (NN * OH * OW)          // 6272 q-groups (n, oh, ow)
#define GRIDP (NQ / 2)             // 3136 pool blocks: 2 q-groups x 2 t-chunks

#define FEATT_BYTES ((size_t)BB * CC * PP * 2)            // 64 MiB
#define STAGE_OFF   FEATT_BYTES
#define STAGE_BYTES ((size_t)NN * BIN * CC * 4)           // 12.8 MB
#define PERM_OFF    (STAGE_OFF + ((STAGE_BYTES + 255) & ~(size_t)255))
#define WS_NEED     (PERM_OFF + NN * 4)

typedef _Float16 hf2 __attribute__((ext_vector_type(2)));

// ------- transpose + downconvert: (B,C,T,H,W) f32 -> (B,T,H,W,C) fp16 -------
__global__ __launch_bounds__(256) void transpose_f16_kernel(
    const float* __restrict__ in, unsigned int* __restrict__ outt /*f16x2*/)
{
    __shared__ float tile[64][65];
    int pb = blockIdx.x & 1023;          // p-tile (1024)
    int cb = (blockIdx.x >> 10) & 3;     // c-tile (4)
    int b  = blockIdx.x >> 12;           // batch (2)

    int tx = threadIdx.x & 63;           // p within tile
    int wv = threadIdx.x >> 6;           // 0..3
    const float* src = in + ((size_t)b * CC + cb * 64) * PP + pb * 64;
    #pragma unroll
    for (int r = 0; r < 16; ++r) {
        int c = wv + r * 4;
        tile[tx][c] = src[(size_t)c * PP + tx];
    }
    __syncthreads();

    int cp   = threadIdx.x & 31;         // c-pair 0..31 (covers 64 c)
    int prow = threadIdx.x >> 5;         // 0..7
    size_t base = ((size_t)b * PP + (size_t)pb * 64) * CC + cb * 64;
    #pragma unroll
    for (int r = 0; r < 8; ++r) {
        int p = prow + r * 8;
        __half h0 = __float2half(tile[p][2 * cp]);
        __half h1 = __float2half(tile[p][2 * cp + 1]);
        unsigned int u = (unsigned int)__half_as_ushort(h0)
                       | ((unsigned int)__half_as_ushort(h1) << 16);
        outt[(base + (size_t)p * CC) / 2 + cp] = u;
    }
}

// ------- Morton-sort ROI indices so consecutive q's are spatially near -------
__global__ __launch_bounds__(128) void sort_rois_kernel(
    const float* __restrict__ rois, int* __restrict__ perm)
{
    __shared__ unsigned int k[NN];
    int t = threadIdx.x;
    const float* r = rois + t * 7;
    int b  = (int)r[0];
    int t1 = (int)r[1], x1 = (int)r[2], y1 = (int)r[3];
    int t2 = (int)r[4], x2 = (int)r[5], y2 = (int)r[6];
    int tc = (t1 + t2) >> 1;             // 0..15
    int yc = ((y1 + y2) >> 1) >> 2;      // 0..15
    int xc = ((x1 + x2) >> 1) >> 2;      // 0..15
    unsigned int m = 0;
    #pragma unroll
    for (int i = 0; i < 4; ++i) {
        m |= (((unsigned)(tc >> i) & 1u) << (3 * i + 2));
        m |= (((unsigned)(yc >> i) & 1u) << (3 * i + 1));
        m |= (((unsigned)(xc >> i) & 1u) << (3 * i));
    }
    unsigned int key = ((unsigned)b << 12) | m;
    k[t] = (key << 8) | (unsigned)t;
    __syncthreads();
    for (int kk = 2; kk <= NN; kk <<= 1) {
        for (int j = kk >> 1; j > 0; j >>= 1) {
            int ixj = t ^ j;
            if (ixj > t) {
                bool up = ((t & kk) == 0);
                unsigned int a = k[t], c = k[ixj];
                if ((a > c) == up) { k[t] = c; k[ixj] = a; }
            }
            __syncthreads();
        }
    }
    perm[t] = (int)(k[t] & 0xFFu);
}

// ---- pipelined gather loop: NX = exact x-width, D = pipeline depth ----
// niter > D: rotating D-deep pipeline; else simple serial loop (best measured:
// the guarded full-issue variant cost ~5.5us across R14/R15).
template<int NX, int D>
__device__ __forceinline__ void pool_loop(
    const unsigned int* __restrict__ p, int niter, int ny,
    int ystep, int tstep, hf2& m0, hf2& m1, hf2& m2, hf2& m3)
{
    uint4 v[D][NX];
    int iy = 0;

#define PLOAD(d)                                            \
    _Pragma("unroll")                                       \
    for (int j = 0; j < NX; ++j)                            \
        v[d][j] = *(const uint4*)(p + j * CU2);

#define PADV()                                              \
    do { if (++iy == ny) { iy = 0; p += tstep; } else p += ystep; } while (0)

#define PCONS(d)                                            \
    _Pragma("unroll")                                       \
    for (int j = 0; j < NX; ++j) {                          \
        m0 = __builtin_elementwise_max(m0, __builtin_bit_cast(hf2, v[d][j].x)); \
        m1 = __builtin_elementwise_max(m1, __builtin_bit_cast(hf2, v[d][j].y)); \
        m2 = __builtin_elementwise_max(m2, __builtin_bit_cast(hf2, v[d][j].z)); \
        m3 = __builtin_elementwise_max(m3, __builtin_bit_cast(hf2, v[d][j].w)); \
    }

    if (niter > D) {
        #pragma unroll
        for (int d = 0; d < D; ++d) { PLOAD(d); PADV(); }
        int M = (niter - D) / D;
        int r = (niter - D) % D;
        for (int s = 0; s < M; ++s) {
            #pragma unroll
            for (int d = 0; d < D; ++d) { PCONS(d); PLOAD(d); PADV(); }
        }
        #pragma unroll
        for (int d = 0; d < D - 1; ++d)
            if (d < r) { PCONS(d); PLOAD(d); PADV(); }
        #pragma unroll
        for (int d = 0; d < D; ++d) PCONS(d);   // max commutative
    } else {
        for (int i = 0; i < niter; ++i) { PLOAD(0); PADV(); PCONS(0); }
    }
#undef PLOAD
#undef PADV
#undef PCONS
}

// ------- pooling: block = 4 waves = 2 q-groups x 2 t-chunks ----------------
__global__ __launch_bounds__(256) void roipool3d_f16_kernel(
    const unsigned int* __restrict__ featt,  // (B,T,H,W,C) f16 as uint pairs
    const float* __restrict__ rois,
    const int* __restrict__ perm,
    float* __restrict__ stage)               // (N, BIN, C) f32
{
    __shared__ unsigned int comb[2][64][4];

    int wg  = blockIdx.x;
    int swz = (wg & 7) * (GRIDP / 8) + (wg >> 3);   // bijective: 3136 % 8 == 0
    int wave  = threadIdx.x >> 6;      // 0..3
    int qslot = wave >> 1;
    int tc    = wave & 1;
    int lane = threadIdx.x & 63;
    int half = lane >> 5;              // = ot
    int cl   = lane & 31;              // c-group: 8 channels
    int q    = swz * 2 + qslot;        // sorted (roi, oh, ow)
    int rem  = q % (OH * OW);
    int n    = perm[q / (OH * OW)];
    int oh   = rem / OW;
    int ow   = rem % OW;

    const float* r = rois + n * 7;
    int b  = (int)r[0];
    int t1 = (int)r[1];
    int x1 = (int)r[2];
    int y1 = (int)r[3];
    int t2 = (int)r[4];
    int x2 = (int)r[5];
    int y2 = (int)r[6];
    int lt = t2 - t1 + 1, lh = y2 - y1 + 1, lw = x2 - x1 + 1;

    int nt_full = (lt + 1) >> 1;       // per-ot t-length (same both halves)
    int ntc0 = (nt_full + 1) >> 1;     // tc=0 chunk length
    int nt_c = tc ? (nt_full - ntc0) : ntc0;      // >= 1
    int t0 = t1 + (half ? (lt >> 1) : 0) + (tc ? ntc0 : 0);

    int hs = (oh * lh) / OH, he = ((oh + 1) * lh + OH - 1) / OH;
    int ws = (ow * lw) / OW, we = ((ow + 1) * lw + OW - 1) / OW;
    int ny = he - hs;                  // 2..6
    int nx = we - ws;                  // 2..6 (wave-uniform)
    int niter = nt_c * ny;             // >= 2

    const unsigned int* p = featt
        + (size_t)((size_t)b * PP + (size_t)((t0 * HH + (y1 + hs)) * WW + (x1 + ws))) * CU2
        + cl * 4;

    const int ystep = WW * CU2;
    const int tstep = (HH - (ny - 1)) * WW * CU2;

    hf2 m0; m0[0] = (_Float16)(-65504.0f); m0[1] = m0[0];
    hf2 m1 = m0, m2 = m0, m3 = m0;

    switch (nx) {
        case 2:  pool_loop<2, 6>(p, niter, ny, ystep, tstep, m0, m1, m2, m3); break;
        case 3:  pool_loop<3, 4>(p, niter, ny, ystep, tstep, m0, m1, m2, m3); break;
        case 4:  pool_loop<4, 3>(p, niter, ny, ystep, tstep, m0, m1, m2, m3); break;
        case 5:  pool_loop<5, 2>(p, niter, ny, ystep, tstep, m0, m1, m2, m3); break;
        default: pool_loop<6, 2>(p, niter, ny, ystep, tstep, m0, m1, m2, m3); break;
    }

    // ---- combine tc partners via LDS; tc=0 writes ----
    if (tc) {
        comb[qslot][lane][0] = __builtin_bit_cast(unsigned int, m0);
        comb[qslot][lane][1] = __builtin_bit_cast(unsigned int, m1);
        comb[qslot][lane][2] = __builtin_bit_cast(unsigned int, m2);
        comb[qslot][lane][3] = __builtin_bit_cast(unsigned int, m3);
    }
    __syncthreads();
    if (!tc) {
        m0 = __builtin_elementwise_max(m0, __builtin_bit_cast(hf2, comb[qslot][lane][0]));
        m1 = __builtin_elementwise_max(m1, __builtin_bit_cast(hf2, comb[qslot][lane][1]));
        m2 = __builtin_elementwise_max(m2, __builtin_bit_cast(hf2, comb[qslot][lane][2]));
        m3 = __builtin_elementwise_max(m3, __builtin_bit_cast(hf2, comb[qslot][lane][3]));

        int c0 = cl * 8;
        int bin = half * (OH * OW) + rem;
        float4 s0 = { (float)m0[0], (float)m0[1], (float)m1[0], (float)m1[1] };
        float4 s1 = { (float)m2[0], (float)m2[1], (float)m3[0], (float)m3[1] };
        float* sp = stage + ((size_t)n * BIN + bin) * CC + c0;
        *(float4*)sp       = s0;
        *(float4*)(sp + 4) = s1;
    }
}

// ------- untranspose: (N, BIN, C) -> (N, C, BIN), both sides coalesced -------
__global__ __launch_bounds__(128) void untranspose_kernel(
    const float* __restrict__ stage, float* __restrict__ out)
{
    __shared__ float t[32][99];
    int n  = blockIdx.x >> 3;
    int c0 = (blockIdx.x & 7) * 32;
    const float* sp = stage + (size_t)n * BIN * CC + c0;
    for (int k = threadIdx.x; k < BIN * 32; k += 128) {
        int bin = k >> 5, c = k & 31;
        t[c][bin] = sp[(size_t)bin * CC + c];
    }
    __syncthreads();
    float* op = out + ((size_t)n * CC + c0) * BIN;
    for (int c = 0; c < 32; ++c) {
        if (threadIdx.x < BIN)
            op[(size_t)c * BIN + threadIdx.x] = t[c][threadIdx.x];
    }
}

// ---------------- fallback if ws too small: direct fp32 gather ----------------
#define NXCD 8
#define C_PER_XCD (CC / NXCD)
#define PLANE (NN * BIN)
#define BLOCKS_PER_C (PLANE / 256)
__global__ __launch_bounds__(256) void roipool3d_fb_kernel(
    const float* __restrict__ feat, const float* __restrict__ rois,
    float* __restrict__ out)
{
    int wg = blockIdx.x, xcd = wg % NXCD, i = wg / NXCD;
    int c = xcd * C_PER_XCD + i / BLOCKS_PER_C;
    int p = (i % BLOCKS_PER_C) * 256 + threadIdx.x;
    int n = p / BIN, rem = p % BIN;
    int ot = rem / (OH * OW), oh = (rem / OW) % OH, ow = rem % OW;
    const float* r = rois + n * 7;
    int b = (int)r[0], t1 = (int)r[1], x1 = (int)r[2], y1 = (int)r[3];
    int t2 = (int)r[4], x2 = (int)r[5], y2 = (int)r[6];
    int lt = t2 - t1 + 1, lh = y2 - y1 + 1, lw = x2 - x1 + 1;
    int ts = (ot * lt) / OT, te = ((ot + 1) * lt + OT - 1) / OT;
    int hs = (oh * lh) / OH, he = ((oh + 1) * lh + OH - 1) / OH;
    int ws = (ow * lw) / OW, we = ((ow + 1) * lw + OW - 1) / OW;
    const float* fbase = feat + ((size_t)b * CC + c) * PP;
    float m = -INFINITY;
    for (int t = t1 + ts; t < t1 + te; ++t)
        for (int y = y1 + hs; y < y1 + he; ++y)
            for (int x = x1 + ws; x < x1 + we; ++x)
                m = fmaxf(m, fbase[t * (HH * WW) + y * WW + x]);
    out[((size_t)n * CC + c) * BIN + rem] = m;
}

extern "C" void kernel_launch(void* const* d_in, const int* in_sizes, int n_in,
                              void* d_out, int out_size, void* d_ws, size_t ws_size,
                              hipStream_t stream) {
    const float* feat = (const float*)d_in[0];
    const float* rois = (const float*)d_in[1];
    float* out = (float*)d_out;

    if (ws_size >= WS_NEED && d_ws) {
        unsigned int* featt = (unsigned int*)d_ws;
        float* stage = (float*)((char*)d_ws + STAGE_OFF);
        int*   perm  = (int*)((char*)d_ws + PERM_OFF);
        sort_rois_kernel<<<1, 128, 0, stream>>>(rois, perm);
        transpose_f16_kernel<<<BB * 4 * 1024, 256, 0, stream>>>(feat, featt);
        roipool3d_f16_kernel<<<GRIDP, 256, 0, stream>>>(featt, rois, perm, stage);
        untranspose_kernel<<<NN * 8, 128, 0, stream>>>(stage, out);
    } else {
        roipool3d_fb_kernel<<<NXCD * C_PER_XCD * BLOCKS_PER_C, 256, 0, stream>>>(
            feat, rois, out);
    }
}